// Round 2
// baseline (883.401 us; speedup 1.0000x reference)
//
#include <hip/hip_runtime.h>
#include <hip/hip_bf16.h>
#include <stdint.h>

typedef __attribute__((ext_vector_type(8))) short bf16x8;
typedef __attribute__((ext_vector_type(4))) float f32x4;

__device__ __forceinline__ float b2f(unsigned short u){
  union { unsigned int i; float f; } x; x.i = ((unsigned int)u) << 16; return x.f;
}
__device__ __forceinline__ unsigned short f2b(float f){
  union { float f; unsigned int i; } x; x.f = f;
  unsigned int r = x.i + 0x7fffu + ((x.i >> 16) & 1u);
  return (unsigned short)(r >> 16);
}

// ---------------- transpose + fp32->bf16: in (R x C) fp32 -> out (C x R) bf16 ----------------
__global__ __launch_bounds__(256) void transpose_k(const float* __restrict__ in,
                                                   unsigned short* __restrict__ out,
                                                   int R, int C){
  __shared__ unsigned short tile[32][33];
  int tx = threadIdx.x & 31, ty = threadIdx.x >> 5;
  int r0 = blockIdx.y * 32, c0 = blockIdx.x * 32;
#pragma unroll
  for (int t = 0; t < 4; ++t)
    tile[ty + t*8][tx] = f2b(in[(size_t)(r0 + ty + t*8) * C + c0 + tx]);
  __syncthreads();
#pragma unroll
  for (int t = 0; t < 4; ++t)
    out[(size_t)(c0 + ty + t*8) * R + r0 + tx] = tile[tx][ty + t*8];
}

// ---------------- ss = silu(t_vec) @ W (1024x2048) + bias -> fp32 ----------------
__global__ __launch_bounds__(256) void ss_k(const float* __restrict__ tvec,
                                            const float* __restrict__ W,
                                            const float* __restrict__ bias,
                                            float* __restrict__ ss){
  int b = blockIdx.y;
  __shared__ float s[1024];
  int tid = threadIdx.x;
#pragma unroll
  for (int t = 0; t < 4; ++t){
    int i = tid + t*256;
    float c = tvec[b*1024 + i];
    s[i] = c / (1.f + __expf(-c));
  }
  __syncthreads();
  int j = blockIdx.x*256 + tid;
  float acc = bias[j];
#pragma unroll 4
  for (int k = 0; k < 1024; ++k)
    acc += s[k] * W[(size_t)k*2048 + j];
  ss[(size_t)b*2048 + j] = acc;
}

// ---------------- adaptive layernorm (fp32 in, bf16 out): per row of H=1024 ----------------
__global__ __launch_bounds__(256) void ada_ln_k(const float* __restrict__ x,
                                                const float* __restrict__ ss,
                                                unsigned short* __restrict__ out,
                                                int L){
  int row = blockIdx.x;
  int b = row / L;
  const float* xr = x + (size_t)row * 1024;
  int tid = threadIdx.x;
  float v[4]; float s = 0.f;
#pragma unroll
  for (int t = 0; t < 4; ++t){ v[t] = xr[tid + t*256]; s += v[t]; }
  __shared__ float red[4];
#pragma unroll
  for (int o = 32; o > 0; o >>= 1) s += __shfl_xor(s, o, 64);
  if ((tid & 63) == 0) red[tid >> 6] = s;
  __syncthreads();
  float mu = (red[0]+red[1]+red[2]+red[3]) * (1.f/1024.f);
  __syncthreads();
  float vs = 0.f;
#pragma unroll
  for (int t = 0; t < 4; ++t){ float d = v[t]-mu; vs += d*d; }
#pragma unroll
  for (int o = 32; o > 0; o >>= 1) vs += __shfl_xor(vs, o, 64);
  if ((tid & 63) == 0) red[tid >> 6] = vs;
  __syncthreads();
  float var = (red[0]+red[1]+red[2]+red[3]) * (1.f/1024.f);
  float inv = rsqrtf(var + 1e-5f);
  const float* sb = ss + (size_t)b*2048;
  unsigned short* orow = out + (size_t)row*1024;
#pragma unroll
  for (int t = 0; t < 4; ++t){
    int i = tid + t*256;
    float h = (v[t]-mu)*inv;
    orow[i] = f2b((1.f + sb[i]) * h + sb[1024 + i]);
  }
}

// ---------------- GEMM: C(MxN) = A(MxK,bf16) @ BT(NxK,bf16)^T + bias(fp32) ----------------
// if Cf != nullptr: write fp32 (+ optional fp32 residual resf); else write bf16 to Cb.
__global__ __launch_bounds__(256) void gemm_bt_k(const unsigned short* __restrict__ A,
                                                 const unsigned short* __restrict__ BT,
                                                 const float* __restrict__ bias,
                                                 const float* __restrict__ resf,
                                                 unsigned short* __restrict__ Cb,
                                                 float* __restrict__ Cf,
                                                 int M, int N, int K){
  __shared__ __attribute__((aligned(16))) unsigned short As[128*32];
  __shared__ __attribute__((aligned(16))) unsigned short Bs[128*32];
  const int tid = threadIdx.x;
  const int wave = tid >> 6, lane = tid & 63;
  const int lm = lane & 15, quad = lane >> 4;
  const int m0 = blockIdx.y * 128, n0 = blockIdx.x * 128;
  const int wm = (wave >> 1) * 64, wn = (wave & 1) * 64;
  f32x4 acc[4][4];
#pragma unroll
  for (int i = 0; i < 4; ++i)
#pragma unroll
    for (int j = 0; j < 4; ++j) acc[i][j] = (f32x4){0.f,0.f,0.f,0.f};

  for (int k0 = 0; k0 < K; k0 += 32){
    __syncthreads();
#pragma unroll
    for (int r = 0; r < 2; ++r){
      int c = r*256 + tid;
      int row = c >> 2, kc = (c & 3) * 8;
      *(bf16x8*)&As[row*32 + kc] = *(const bf16x8*)&A[(size_t)(m0 + row)*K + k0 + kc];
      *(bf16x8*)&Bs[row*32 + kc] = *(const bf16x8*)&BT[(size_t)(n0 + row)*K + k0 + kc];
    }
    __syncthreads();
    bf16x8 af[4], bfr[4];
#pragma unroll
    for (int i = 0; i < 4; ++i)
      af[i] = *(bf16x8*)&As[(wm + i*16 + lm)*32 + quad*8];
#pragma unroll
    for (int j = 0; j < 4; ++j)
      bfr[j] = *(bf16x8*)&Bs[(wn + j*16 + lm)*32 + quad*8];
#pragma unroll
    for (int i = 0; i < 4; ++i)
#pragma unroll
      for (int j = 0; j < 4; ++j)
        acc[i][j] = __builtin_amdgcn_mfma_f32_16x16x32_bf16(af[i], bfr[j], acc[i][j], 0, 0, 0);
  }

#pragma unroll
  for (int j = 0; j < 4; ++j){
    int col = n0 + wn + j*16 + lm;
    float bv = bias[col];
#pragma unroll
    for (int i = 0; i < 4; ++i){
#pragma unroll
      for (int p = 0; p < 4; ++p){
        int row = m0 + wm + i*16 + quad*4 + p;
        float v = acc[i][j][p] + bv;
        if (Cf){
          if (resf) v += resf[(size_t)row*N + col];
          Cf[(size_t)row*N + col] = v;
        } else {
          Cb[(size_t)row*N + col] = f2b(v);
        }
      }
    }
  }
}

// ---------------- attention: per block = (b, h, 64-row q tile), all bf16 ----------------
// q: (B,2048,1024); kv: (B,512,2048) (k = cols [0,1024), v = cols [1024,2048))
__global__ __launch_bounds__(256) void attn_k(const unsigned short* __restrict__ q,
                                              const unsigned short* __restrict__ kv,
                                              unsigned short* __restrict__ out){
  const int qb = blockIdx.x, h = blockIdx.y, b = blockIdx.z;
  const int tid = threadIdx.x;
  const int wave = tid >> 6, lane = tid & 63;
  const int lm = lane & 15, quad = lane >> 4;
  const int q0 = qb * 64;

  __shared__ __attribute__((aligned(16))) unsigned short Qs[64*64];
  __shared__ __attribute__((aligned(16))) unsigned short Ks[128*64];
  __shared__ __attribute__((aligned(16))) unsigned short Ps[4][16*64];
  __shared__ __attribute__((aligned(16))) unsigned short Vt[64*64];

  const size_t qbase = ((size_t)b*2048 + q0) * 1024 + h*64;
#pragma unroll
  for (int r = 0; r < 2; ++r){
    int c = r*256 + tid;
    int row = c >> 3, dc = (c & 7) * 8;
    *(bf16x8*)&Qs[row*64 + dc] = *(const bf16x8*)&q[qbase + (size_t)row*1024 + dc];
  }

  f32x4 sacc[32];
#pragma unroll
  for (int t = 0; t < 32; ++t) sacc[t] = (f32x4){0.f,0.f,0.f,0.f};

  const size_t kbase = (size_t)b*512*2048 + h*64;
  for (int kt = 0; kt < 4; ++kt){
    __syncthreads();
#pragma unroll
    for (int r = 0; r < 4; ++r){
      int c = r*256 + tid;
      int lrow = c >> 3, dc = (c & 7) * 8;
      *(bf16x8*)&Ks[lrow*64 + dc] =
          *(const bf16x8*)&kv[kbase + (size_t)(kt*128 + lrow)*2048 + dc];
    }
    __syncthreads();
    bf16x8 af[2];
#pragma unroll
    for (int ds = 0; ds < 2; ++ds)
      af[ds] = *(bf16x8*)&Qs[(wave*16 + lm)*64 + ds*32 + quad*8];
#pragma unroll
    for (int nt = 0; nt < 8; ++nt){
#pragma unroll
      for (int ds = 0; ds < 2; ++ds){
        bf16x8 bfr = *(bf16x8*)&Ks[(nt*16 + lm)*64 + ds*32 + quad*8];
        sacc[kt*8 + nt] = __builtin_amdgcn_mfma_f32_16x16x32_bf16(af[ds], bfr, sacc[kt*8 + nt], 0, 0, 0);
      }
    }
  }

  // softmax over 512 cols; row r = quad*4+p lives in a fixed 16-lane group
  float m4[4] = {-1e30f,-1e30f,-1e30f,-1e30f};
#pragma unroll
  for (int t = 0; t < 32; ++t)
#pragma unroll
    for (int p = 0; p < 4; ++p){
      float vv = sacc[t][p] * 0.125f;   // 1/sqrt(64)
      sacc[t][p] = vv;
      m4[p] = fmaxf(m4[p], vv);
    }
#pragma unroll
  for (int p = 0; p < 4; ++p)
#pragma unroll
    for (int o = 1; o < 16; o <<= 1)
      m4[p] = fmaxf(m4[p], __shfl_xor(m4[p], o, 64));
  float l4[4] = {0.f,0.f,0.f,0.f};
#pragma unroll
  for (int t = 0; t < 32; ++t)
#pragma unroll
    for (int p = 0; p < 4; ++p){
      float e = __expf(sacc[t][p] - m4[p]);
      sacc[t][p] = e;
      l4[p] += e;
    }
#pragma unroll
  for (int p = 0; p < 4; ++p)
#pragma unroll
    for (int o = 1; o < 16; o <<= 1)
      l4[p] += __shfl_xor(l4[p], o, 64);
  float rinv[4];
#pragma unroll
  for (int p = 0; p < 4; ++p) rinv[p] = 1.f / l4[p];

  // O = P @ V, l-tiles of 64
  f32x4 oacc[4];
#pragma unroll
  for (int nt = 0; nt < 4; ++nt) oacc[nt] = (f32x4){0.f,0.f,0.f,0.f};
  const size_t vbase = (size_t)b*512*2048 + 1024 + h*64;
  for (int lt = 0; lt < 8; ++lt){
    __syncthreads();
    // stage V^T (d x l) into LDS
#pragma unroll
    for (int r = 0; r < 2; ++r){
      int c = r*256 + tid;
      int l = c >> 3, dc = (c & 7) * 8;
      bf16x8 t8 = *(const bf16x8*)&kv[vbase + (size_t)(lt*64 + l)*2048 + dc];
      union { bf16x8 v; short u[8]; } uu; uu.v = t8;
#pragma unroll
      for (int u = 0; u < 8; ++u)
        Vt[(dc + u)*64 + l] = (unsigned short)uu.u[u];
    }
    // write this wave's P subtile (16 x 64), row-major for A-frag reads
#pragma unroll
    for (int s = 0; s < 4; ++s){
      int t = lt*4 + s;
#pragma unroll
      for (int p = 0; p < 4; ++p)
        Ps[wave][(quad*4 + p)*64 + s*16 + lm] = f2b(sacc[t][p]);
    }
    __syncthreads();
#pragma unroll
    for (int ks = 0; ks < 2; ++ks){
      bf16x8 af = *(bf16x8*)&Ps[wave][lm*64 + ks*32 + quad*8];
#pragma unroll
      for (int nt = 0; nt < 4; ++nt){
        bf16x8 bfr = *(bf16x8*)&Vt[(nt*16 + lm)*64 + ks*32 + quad*8];
        oacc[nt] = __builtin_amdgcn_mfma_f32_16x16x32_bf16(af, bfr, oacc[nt], 0, 0, 0);
      }
    }
  }

  const size_t obase = ((size_t)b*2048 + q0 + wave*16) * 1024 + h*64;
#pragma unroll
  for (int nt = 0; nt < 4; ++nt)
#pragma unroll
    for (int p = 0; p < 4; ++p){
      int row = quad*4 + p;
      out[obase + (size_t)row*1024 + nt*16 + lm] = f2b(oacc[nt][p] * rinv[p]);
    }
}

extern "C" void kernel_launch(void* const* d_in, const int* in_sizes, int n_in,
                              void* d_out, int out_size, void* d_ws, size_t ws_size,
                              hipStream_t stream){
  // All inputs are fp32 per the reference; output fp32.
  const float* x_q  = (const float*)d_in[0];
  const float* x_kv = (const float*)d_in[1];
  const float* tvec = (const float*)d_in[2];
  const float* Wq   = (const float*)d_in[3];
  const float* bq   = (const float*)d_in[4];
  const float* Wkv  = (const float*)d_in[5];
  const float* bkv  = (const float*)d_in[6];
  const float* Wp   = (const float*)d_in[7];
  const float* bp   = (const float*)d_in[8];
  const float* Wssq = (const float*)d_in[9];
  const float* bssq = (const float*)d_in[10];
  const float* Wssk = (const float*)d_in[11];
  const float* bssk = (const float*)d_in[12];

  char* ws = (char*)d_ws;
  float*          ss_q  = (float*)(ws + 0);                    // 64 KB
  float*          ss_kv = (float*)(ws + 65536);                // 64 KB
  unsigned short* xq    = (unsigned short*)(ws + 131072);      // 32 MB bf16; reused as attn out
  unsigned short* xkv   = (unsigned short*)(ws + 33685504);    // 8 MB bf16
  unsigned short* qbuf  = (unsigned short*)(ws + 42074112);    // 32 MB bf16
  unsigned short* kvbuf = (unsigned short*)(ws + 75628544);    // 16 MB bf16
  unsigned short* WqT   = (unsigned short*)(ws + 92405760);    // 2 MB bf16
  unsigned short* WkvT  = (unsigned short*)(ws + 94502912);    // 4 MB bf16
  unsigned short* WpT   = (unsigned short*)(ws + 98697216);    // 2 MB bf16

  dim3 blk(256);
  transpose_k<<<dim3(32, 32), blk, 0, stream>>>(Wq,  WqT,  1024, 1024);
  transpose_k<<<dim3(64, 32), blk, 0, stream>>>(Wkv, WkvT, 1024, 2048);
  transpose_k<<<dim3(32, 32), blk, 0, stream>>>(Wp,  WpT,  1024, 1024);

  ss_k<<<dim3(8, 8), blk, 0, stream>>>(tvec, Wssq, bssq, ss_q);
  ss_k<<<dim3(8, 8), blk, 0, stream>>>(tvec, Wssk, bssk, ss_kv);

  ada_ln_k<<<dim3(16384), blk, 0, stream>>>(x_q,  ss_q,  xq,  2048);
  ada_ln_k<<<dim3(4096),  blk, 0, stream>>>(x_kv, ss_kv, xkv, 512);

  gemm_bt_k<<<dim3(8, 128), blk, 0, stream>>>(xq,  WqT,  bq,  nullptr, qbuf,  nullptr, 16384, 1024, 1024);
  gemm_bt_k<<<dim3(16, 32), blk, 0, stream>>>(xkv, WkvT, bkv, nullptr, kvbuf, nullptr, 4096,  2048, 1024);

  attn_k<<<dim3(32, 16, 8), blk, 0, stream>>>(qbuf, kvbuf, xq);

  gemm_bt_k<<<dim3(8, 128), blk, 0, stream>>>(xq, WpT, bp, x_q, nullptr,
                                              (float*)d_out, 16384, 1024, 1024);
}